// Round 12
// baseline (536.209 us; speedup 1.0000x reference)
//
#include <hip/hip_runtime.h>

#define HEADS 6
#define N_TOK 144
#define DIM   192
#define NW    64
#define NB    15
#define NBW   (NB * NW)          // 960

typedef __attribute__((ext_vector_type(8))) short bf16x8;
typedef __attribute__((ext_vector_type(4))) float f32x4;

#define MFMA(a, b, c) __builtin_amdgcn_mfma_f32_16x16x32_bf16(a, b, c, 0, 0, 0)

static __device__ __forceinline__ short f2bf(float f) {
    union { float f; unsigned u; } v; v.f = f;
    unsigned r = v.u + 0x7FFFu + ((v.u >> 16) & 1u);   // RNE
    return (short)(r >> 16);
}
static __device__ __forceinline__ float bf2f(short s) {
    union { unsigned u; float f; } v;
    v.u = ((unsigned)(unsigned short)s) << 16;
    return v.f;
}
static __device__ __forceinline__ unsigned pk2(float a, float b) {
    return (unsigned)(unsigned short)f2bf(a) |
           ((unsigned)(unsigned short)f2bf(b) << 16);
}

// ---------------------------------------------------------------------------
// K0a: bias gather -> bf16, layout [(w*6+h)][i*144+j].
// ---------------------------------------------------------------------------
__global__ __launch_bounds__(256)
void bias_k(const float* __restrict__ table, const int* __restrict__ pos_index,
            short* __restrict__ bias_bf) {
    const int t = blockIdx.x;                      // w*6+h, 0..383
    for (int e = threadIdx.x; e < N_TOK * N_TOK; e += 256) {
        int idx = pos_index[e];
        bias_bf[(long)t * (N_TOK * N_TOK) + e] = f2bf(table[(long)idx * 384 + t]);
    }
}

// K0b: f32 -> bf16 copy (weights)
__global__ __launch_bounds__(256)
void cvt_k(const float* __restrict__ w, short* __restrict__ o, int n) {
    int i = blockIdx.x * 256 + threadIdx.x;
    if (i < n) o[i] = f2bf(w[i]);
}

// ---------------------------------------------------------------------------
// K1: per-(bw,head) fused QKV + attention. 5760 blocks, 9 waves, wave = 16
// q-rows. No HBM intermediates for q/k/v: each wave loads its 16 x-rows as
// f32 (converted in-reg, af 6x bf16x8), does 36 MFMA against L2-resident
// bf16 qkv_w for head h; q -> per-wave pws, k -> klds[144][40],
// v -> vlds[32][156] (transposed); ONE barrier; swapped QK^T (lane holds
// S[k 4-consec][q=lane&15]); bias short4 + mask (preloaded regs); softmax
// (2 shuffles); P packed u32 -> pws streaming; PV = MFMA(V^T, P);
// coalesced short4 tmp writes.
// XCD swizzle (5760 = 8*720): a bw's 6 head-blocks share an XCD -> its x
// slice (110 KB) and mask (83 KB) are L2-hot after the first head.
// ---------------------------------------------------------------------------
__global__ __launch_bounds__(576, 2)
void attnqkv_k(const float* __restrict__ x, const short* __restrict__ qkvw_bf,
               const float* __restrict__ qkv_b, const short* __restrict__ bias_bf,
               const float* __restrict__ mask, short* __restrict__ tmp) {
    __shared__ short klds[N_TOK * 40];     // 11,520 B
    __shared__ short vlds[32 * 156];       //  9,984 B
    __shared__ short pws[9 * 16 * 40];     // 11,520 B   (33 KB total)

    const int p  = blockIdx.x;
    const int l  = (p & 7) * 720 + (p >> 3);   // bijective: 5760 = 8*720
    const int h  = l % HEADS;
    const int bw = l / HEADS;
    const int tid = threadIdx.x;
    const int lane = tid & 63, lq = lane & 15, lg = lane >> 4;
    const int wid = tid >> 6;
    const int m0 = wid * 16;
    const int q  = m0 + lq;                // this lane's query/x row
    const int w  = bw & 63;
    const float scale = 0.17677669529663687f;   // 32^-0.5

    // ---- x A-frags (row q, all 192 ch) -> 24 VGPR ----
    bf16x8 af[6];
    {
        const float* xg = x + ((long)bw * N_TOK + q) * DIM;
        #pragma unroll
        for (int ks = 0; ks < 6; ++ks) {
            const float4* pp = (const float4*)&xg[ks * 32 + 8 * lg];
            float4 f0 = pp[0], f1 = pp[1];
            bf16x8 a;
            a[0]=f2bf(f0.x); a[1]=f2bf(f0.y); a[2]=f2bf(f0.z); a[3]=f2bf(f0.w);
            a[4]=f2bf(f1.x); a[5]=f2bf(f1.y); a[6]=f2bf(f1.z); a[7]=f2bf(f1.w);
            af[ks] = a;
        }
    }

    // ---- mask preload (issue early for MLP): 9 float4 ----
    float4 mreg[9];
    {
        const float* mp = mask + (long)bw * (N_TOK * N_TOK) + q * N_TOK + 4 * lg;
        #pragma unroll
        for (int nt = 0; nt < 9; ++nt) mreg[nt] = *(const float4*)&mp[nt * 16];
    }

    short* pw = pws + wid * 16 * 40;
    const f32x4 zf = {};
    const bf16x8 zb = {};

    // ---- QKV GEMM for head h: wave's 16 rows x (3 sel x 32 ch) ----
    f32x4 acc[3][2] = {};
    #pragma unroll
    for (int ks = 0; ks < 6; ++ks)
        #pragma unroll
        for (int sel = 0; sel < 3; ++sel)
            #pragma unroll
            for (int nt = 0; nt < 2; ++nt) {
                bf16x8 b = *(const bf16x8*)&qkvw_bf[
                    ((long)sel * 192 + h * 32 + nt * 16 + lq) * 192 + ks * 32 + 8 * lg];
                acc[sel][nt] = MFMA(af[ks], b, acc[sel][nt]);
            }

    // q -> per-wave pw [16][40] (own region, no barrier needed)
    #pragma unroll
    for (int nt = 0; nt < 2; ++nt) {
        float bb = qkv_b[h * 32 + nt * 16 + lq];
        #pragma unroll
        for (int i = 0; i < 4; ++i)
            pw[(4 * lg + i) * 40 + nt * 16 + lq] =
                f2bf((acc[0][nt][i] + bb) * scale);
    }

    // k, v -> LDS
    #pragma unroll
    for (int nt = 0; nt < 2; ++nt) {
        float bk = qkv_b[192 + h * 32 + nt * 16 + lq];
        float bv = qkv_b[384 + h * 32 + nt * 16 + lq];
        #pragma unroll
        for (int i = 0; i < 4; ++i) {
            klds[(m0 + 4 * lg + i) * 40 + nt * 16 + lq] = f2bf(acc[1][nt][i] + bk);
            vlds[(nt * 16 + lq) * 156 + m0 + 4 * lg + i] = f2bf(acc[2][nt][i] + bv);
        }
    }
    __syncthreads();   // k, v visible to all waves

    // ---- QK^T (swapped: A=K tile, B=Q tile) ----
    bf16x8 bq = *(const bf16x8*)&pw[lq * 40 + 8 * lg];
    f32x4 lgt[9];
    #pragma unroll
    for (int nt = 0; nt < 9; ++nt) {
        bf16x8 ak = *(const bf16x8*)&klds[(nt * 16 + lq) * 40 + 8 * lg];
        lgt[nt] = MFMA(ak, bq, zf);
    }

    // ---- + bias (short4, L3-hot) + mask (regs) ----
    const short* bp = bias_bf + (long)(w * 6 + h) * (N_TOK * N_TOK)
                    + q * N_TOK + 4 * lg;
    #pragma unroll
    for (int nt = 0; nt < 9; ++nt) {
        short4 bs = *(const short4*)&bp[nt * 16];
        lgt[nt][0] += bf2f(bs.x) + mreg[nt].x;
        lgt[nt][1] += bf2f(bs.y) + mreg[nt].y;
        lgt[nt][2] += bf2f(bs.z) + mreg[nt].z;
        lgt[nt][3] += bf2f(bs.w) + mreg[nt].w;
    }

    // ---- softmax over k (36 in-lane + xor16/xor32) ----
    float m = lgt[0][0];
    #pragma unroll
    for (int nt = 0; nt < 9; ++nt)
        #pragma unroll
        for (int i = 0; i < 4; ++i) m = fmaxf(m, lgt[nt][i]);
    m = fmaxf(m, __shfl_xor(m, 16));
    m = fmaxf(m, __shfl_xor(m, 32));
    float s = 0.f;
    #pragma unroll
    for (int nt = 0; nt < 9; ++nt)
        #pragma unroll
        for (int i = 0; i < 4; ++i) {
            float pe = __expf(lgt[nt][i] - m);
            lgt[nt][i] = pe;
            s += pe;
        }
    s += __shfl_xor(s, 16);
    s += __shfl_xor(s, 32);
    const float inv = 1.f / s;

    // ---- PV: stream packed P through pw; o = MFMA(V^T-frag, P-frag) ----
    f32x4 o[2] = {};
    #pragma unroll
    for (int kt = 0; kt < 5; ++kt) {
        const int nt0 = 2 * kt;
        *(unsigned*)&pw[lq * 40 + 4 * lg]     = pk2(lgt[nt0][0], lgt[nt0][1]);
        *(unsigned*)&pw[lq * 40 + 4 * lg + 2] = pk2(lgt[nt0][2], lgt[nt0][3]);
        if (kt < 4) {
            const int nt1 = nt0 + 1;
            *(unsigned*)&pw[lq * 40 + 16 + 4 * lg]     = pk2(lgt[nt1][0], lgt[nt1][1]);
            *(unsigned*)&pw[lq * 40 + 16 + 4 * lg + 2] = pk2(lgt[nt1][2], lgt[nt1][3]);
        }
        bf16x8 bpf = *(const bf16x8*)&pw[lq * 40 + 8 * lg];
        #pragma unroll
        for (int et = 0; et < 2; ++et) {
            bf16x8 av = *(const bf16x8*)&vlds[(et * 16 + lq) * 156 + kt * 32 + 8 * lg];
            bf16x8 aa = av, bb = bpf;
            if (kt == 4 && lg >= 2) { aa = zb; bb = zb; }   // keys 144..159
            o[et] = MFMA(aa, bb, o[et]);
        }
    }

    // ---- write tmp[bw][q][h*32 + e] (short4) ----
    short* tb = tmp + ((long)bw * N_TOK + q) * DIM + h * 32;
    #pragma unroll
    for (int et = 0; et < 2; ++et) {
        short4 sx = { f2bf(o[et][0] * inv), f2bf(o[et][1] * inv),
                      f2bf(o[et][2] * inv), f2bf(o[et][3] * inv) };
        *(short4*)&tb[et * 16 + 4 * lg] = sx;
    }
}

// ---------------------------------------------------------------------------
// K2: output projection. Block = (bw, m-third) via matching bw->XCD swizzle
// (tmp L2 locality with K1). 3 waves, wave = 16 rows. A from tmp bf16,
// B from L2-resident bf16 proj_w.
// ---------------------------------------------------------------------------
__global__ __launch_bounds__(192)
void proj_k(const short* __restrict__ tmp, const short* __restrict__ pwt,
            const float* __restrict__ proj_b, float* __restrict__ out) {
    const int p = blockIdx.x;
    const int l = (p & 7) * 360 + (p >> 3);   // bijective: 2880 = 8*360
    const int third = l % 3;
    const int bw    = l / 3;
    const int tid = threadIdx.x;
    const int wid = tid >> 6, lane = tid & 63, lq = lane & 15, lg = lane >> 4;
    const int m0 = (third * 3 + wid) * 16;
    const short* tb = tmp + (long)bw * N_TOK * DIM;

    f32x4 acc[12] = {};
    for (int ks = 0; ks < 6; ++ks) {
        const int k0 = ks * 32 + 8 * lg;
        bf16x8 a = *(const bf16x8*)&tb[(m0 + lq) * DIM + k0];
        #pragma unroll
        for (int nt = 0; nt < 12; ++nt) {
            bf16x8 b = *(const bf16x8*)&pwt[(nt * 16 + lq) * DIM + k0];
            acc[nt] = MFMA(a, b, acc[nt]);
        }
    }
    float* ob = out + (long)bw * N_TOK * DIM;
    #pragma unroll
    for (int nt = 0; nt < 12; ++nt) {
        float pb = proj_b[nt * 16 + lq];
        #pragma unroll
        for (int i = 0; i < 4; ++i)
            ob[(m0 + 4 * lg + i) * DIM + nt * 16 + lq] = acc[nt][i] + pb;
    }
}

// ---------------------------------------------------------------------------
extern "C" void kernel_launch(void* const* d_in, const int* in_sizes, int n_in,
                              void* d_out, int out_size, void* d_ws, size_t ws_size,
                              hipStream_t stream) {
    const float* x        = (const float*)d_in[0];
    const float* mask     = (const float*)d_in[1];
    const float* qkv_w    = (const float*)d_in[2];
    const float* qkv_b    = (const float*)d_in[3];
    const float* table    = (const float*)d_in[4];
    const float* proj_w   = (const float*)d_in[5];
    const float* proj_b   = (const float*)d_in[6];
    const int*   pos_index= (const int*)d_in[7];
    float* out = (float*)d_out;

    // ws layout (bf16 shorts), total ~69.3 MB:
    //  bias_bf  [384][144*144]        15.93 MB
    //  projw_bf [192*192]              0.07 MB
    //  qkvw_bf  [576*192]              0.22 MB
    //  tmp_ws   [960 x 144 x 192]     53.08 MB
    short* bias_bf  = (short*)d_ws;
    short* projw_bf = bias_bf + (size_t)384 * N_TOK * N_TOK;
    short* qkvw_bf  = projw_bf + 36864;
    short* tmp_ws   = qkvw_bf + 110592;

    bias_k<<<384, 256, 0, stream>>>(table, pos_index, bias_bf);
    cvt_k<<<144, 256, 0, stream>>>(proj_w, projw_bf, DIM * DIM);
    cvt_k<<<432, 256, 0, stream>>>(qkv_w, qkvw_bf, 3 * DIM * DIM);

    attnqkv_k<<<NBW * HEADS, 576, 0, stream>>>(x, qkvw_bf, qkv_b, bias_bf,
                                               mask, tmp_ws);
    proj_k<<<NBW * 3, 192, 0, stream>>>(tmp_ws, projw_bf, proj_b, out);
}

// Round 13
// 464.527 us; speedup vs baseline: 1.1543x; 1.1543x over previous
//
#include <hip/hip_runtime.h>

#define HEADS 6
#define N_TOK 144
#define DIM   192
#define NW    64
#define NB    15
#define NBW   (NB * NW)          // 960
#define CHUNK 480                // bw per chunk (2 chunks)

typedef __attribute__((ext_vector_type(8))) short bf16x8;
typedef __attribute__((ext_vector_type(4))) float f32x4;

#define MFMA(a, b, c) __builtin_amdgcn_mfma_f32_16x16x32_bf16(a, b, c, 0, 0, 0)

static __device__ __forceinline__ short f2bf(float f) {
    union { float f; unsigned u; } v; v.f = f;
    unsigned r = v.u + 0x7FFFu + ((v.u >> 16) & 1u);   // RNE
    return (short)(r >> 16);
}
static __device__ __forceinline__ float bf2f(short s) {
    union { unsigned u; float f; } v;
    v.u = ((unsigned)(unsigned short)s) << 16;
    return v.f;
}
static __device__ __forceinline__ unsigned pk2(float a, float b) {
    return (unsigned)(unsigned short)f2bf(a) |
           ((unsigned)(unsigned short)f2bf(b) << 16);
}

// ---------------------------------------------------------------------------
// K0a: bias gather -> bf16, layout [(w*6+h)][i*144+j].
// ---------------------------------------------------------------------------
__global__ __launch_bounds__(256)
void bias_k(const float* __restrict__ table, const int* __restrict__ pos_index,
            short* __restrict__ bias_bf) {
    const int t = blockIdx.x;                      // w*6+h, 0..383
    for (int e = threadIdx.x; e < N_TOK * N_TOK; e += 256) {
        int idx = pos_index[e];
        bias_bf[(long)t * (N_TOK * N_TOK) + e] = f2bf(table[(long)idx * 384 + t]);
    }
}

// K0b: f32 -> bf16 scalar copy (weights)
__global__ __launch_bounds__(256)
void cvt_k(const float* __restrict__ w, short* __restrict__ o, int n) {
    int i = blockIdx.x * 256 + threadIdx.x;
    if (i < n) o[i] = f2bf(w[i]);
}

// ---------------------------------------------------------------------------
// K1: QKV GEMM, 192-thread blocks (the 62%-occupancy shape). Block =
// (bwL, sel, mg): 3 waves = 3 ng-groups; wave tile 48x64 (acc in AGPRs).
// x mg-slice staged f32->bf16 in-block (cvtx eliminated); W B-frags from
// L2-resident bf16 qkv_w (proven by proj_k at 4.2 TB/s). Epilogue: LDS
// restage -> coalesced bf16x8 stores (qk row-major; v transposed, 96 B
// 32B-aligned runs -> sector-clean).
// XCD swizzle (4320 = 8*540) clusters a bw's 9 blocks for x L2 reuse.
// ---------------------------------------------------------------------------
__global__ __launch_bounds__(192)
void qkvs192_k(const float* __restrict__ x, const short* __restrict__ qkvw_bf,
               const float* __restrict__ qkv_b, short* __restrict__ qk_ws,
               short* __restrict__ vT_ws, int bw0) {
    __shared__ short xl[192 * 56];   // 21,504 B; [48][200] stage / [192][56] v

    const int p = blockIdx.x;
    const int l = (p & 7) * 540 + (p >> 3);    // bijective: 4320 = 8*540
    const int mg  = l % 3;
    const int sel = (l / 3) % 3;
    const int bwL = l / 9;
    const int bwG = bw0 + bwL;
    const int tid = threadIdx.x;

    // ---- stage x rows [mg*48, +48) as bf16 [48][200] ----
    {
        const float* xg = x + ((long)bwG * N_TOK + mg * 48) * DIM;
        for (int u = tid * 4; u < 48 * DIM; u += 192 * 4) {
            float4 f = *(const float4*)&xg[u];
            short4 s = { f2bf(f.x), f2bf(f.y), f2bf(f.z), f2bf(f.w) };
            int r = u / DIM, c = u - r * DIM;
            *(short4*)&xl[r * 200 + c] = s;
        }
    }
    __syncthreads();

    const int wid = tid >> 6, lane = tid & 63, lq = lane & 15, lg = lane >> 4;
    const int ng = wid;

    f32x4 acc[3][4] = {};
    for (int ks = 0; ks < 6; ++ks) {
        const int k0 = ks * 32 + 8 * lg;
        bf16x8 av[3], bv[4];
        #pragma unroll
        for (int mt = 0; mt < 3; ++mt)
            av[mt] = *(const bf16x8*)&xl[(mt * 16 + lq) * 200 + k0];
        #pragma unroll
        for (int nt = 0; nt < 4; ++nt)
            bv[nt] = *(const bf16x8*)&qkvw_bf[
                ((long)sel * 192 + ng * 64 + nt * 16 + lq) * 192 + k0];
        #pragma unroll
        for (int mt = 0; mt < 3; ++mt)
            #pragma unroll
            for (int nt = 0; nt < 4; ++nt)
                acc[mt][nt] = MFMA(av[mt], bv[nt], acc[mt][nt]);
    }
    __syncthreads();   // done reading xl -> reuse for restage

    const float scale = 0.17677669529663687f;   // 32^-0.5

    if (sel < 2) {
        // ---- row-major restage [48][200] ----
        #pragma unroll
        for (int nt = 0; nt < 4; ++nt) {
            const int cd = ng * 64 + nt * 16 + lq;          // 0..191
            const float bb = qkv_b[sel * 192 + cd];
            #pragma unroll
            for (int mt = 0; mt < 3; ++mt)
                #pragma unroll
                for (int i = 0; i < 4; ++i) {
                    int row = mt * 16 + 4 * lg + i;          // 0..47
                    float v = acc[mt][nt][i] + bb;
                    if (sel == 0) v *= scale;
                    xl[row * 200 + cd] = f2bf(v);
                }
        }
        __syncthreads();
        // coalesced copy out: 9216 elems, 6 iters of bf16x8
        short* ob = qk_ws + (long)bwL * 6 * 2 * 4608 + (long)sel * 4608
                  + mg * 48 * 32;
        #pragma unroll
        for (int j = 0; j < 6; ++j) {
            int u = (j * 192 + tid) * 8;        // 0..9215
            int h = u / 1536, rem = u - h * 1536;
            int row = rem >> 5, e = rem & 31;
            *(bf16x8*)&ob[(long)h * 2 * 4608 + row * 32 + e] =
                *(const bf16x8*)&xl[row * 200 + h * 32 + e];
        }
    } else {
        // ---- col-major restage [192][56] ----
        #pragma unroll
        for (int nt = 0; nt < 4; ++nt) {
            const int cd = ng * 64 + nt * 16 + lq;          // 0..191
            const float bb = qkv_b[2 * 192 + cd];
            #pragma unroll
            for (int mt = 0; mt < 3; ++mt)
                #pragma unroll
                for (int i = 0; i < 4; ++i) {
                    int row = mt * 16 + 4 * lg + i;          // 0..47
                    xl[cd * 56 + row] = f2bf(acc[mt][nt][i] + bb);
                }
        }
        __syncthreads();
        // coalesced copy out: 192 (h,e)-rows x 48 cols, 6 iters of bf16x8
        short* ob = vT_ws + (long)bwL * 6 * 4608 + mg * 48;
        #pragma unroll
        for (int j = 0; j < 6; ++j) {
            int u = (j * 192 + tid) * 8;        // 0..9215
            int he = u / 48, row0 = u - he * 48;
            *(bf16x8*)&ob[(long)he * 144 + row0] =
                *(const bf16x8*)&xl[he * 56 + row0];
        }
    }
}

// ---------------------------------------------------------------------------
// K2 (unchanged from R11): 3-wave attention, barrier-free. Block =
// (bwL, head, third). Swapped QK^T from global; softmax in-wave; full P tile
// -> per-wave LDS [16][168]; PV streams ds_read_b128 + global V^T frags.
// ---------------------------------------------------------------------------
__global__ __launch_bounds__(192, 6)
void attn3w_k(const short* __restrict__ qk_ws, const short* __restrict__ vT_ws,
              const short* __restrict__ bias_bf, const float* __restrict__ mask,
              short* __restrict__ tmp, int bw0) {
    __shared__ short pws[3 * 16 * 168];   // 16,128 B

    // XCD chunking: grid = CHUNK*18 = 8640 = 8 * 1080
    const int p = blockIdx.x;
    const int l = (p & 7) * 1080 + (p >> 3);
    const int third = l % 3;
    const int h     = (l / 3) % HEADS;
    const int bwL   = l / 18;
    const int bwG   = bw0 + bwL;
    const int lane = threadIdx.x & 63, lq = lane & 15, lg = lane >> 4;
    const int wid = threadIdx.x >> 6;
    const int mt9 = third * 3 + wid;       // m-tile 0..8
    const int q = mt9 * 16 + lq;            // this lane's query row
    const int w = bwG & 63;

    const short* qb = qk_ws + (long)(bwL * 6 + h) * 2 * 4608;
    const short* kb = qb + 4608;

    // ---- QK^T (swapped: A=K tile, B=Q tile) ----
    const f32x4 zf = {};
    bf16x8 bq = *(const bf16x8*)&qb[q * 32 + 8 * lg];
    f32x4 lgt[9];
    #pragma unroll
    for (int nt = 0; nt < 9; ++nt) {
        bf16x8 ak = *(const bf16x8*)&kb[(nt * 16 + lq) * 32 + 8 * lg];
        lgt[nt] = MFMA(ak, bq, zf);
    }

    // ---- + bias (short4) + mask (float4) ----
    const short* bp = bias_bf + (long)(w * 6 + h) * (N_TOK * N_TOK)
                    + q * N_TOK + 4 * lg;
    const float* mp = mask + (long)bwG * (N_TOK * N_TOK) + q * N_TOK + 4 * lg;
    #pragma unroll
    for (int nt = 0; nt < 9; ++nt) {
        short4 bs = *(const short4*)&bp[nt * 16];
        float4 mf = *(const float4*)&mp[nt * 16];
        lgt[nt][0] += bf2f(bs.x) + mf.x;
        lgt[nt][1] += bf2f(bs.y) + mf.y;
        lgt[nt][2] += bf2f(bs.z) + mf.z;
        lgt[nt][3] += bf2f(bs.w) + mf.w;
    }

    // ---- softmax over k (36 in-lane + xor16/xor32) ----
    float m = lgt[0][0];
    #pragma unroll
    for (int nt = 0; nt < 9; ++nt)
        #pragma unroll
        for (int i = 0; i < 4; ++i) m = fmaxf(m, lgt[nt][i]);
    m = fmaxf(m, __shfl_xor(m, 16));
    m = fmaxf(m, __shfl_xor(m, 32));
    float s = 0.f;
    #pragma unroll
    for (int nt = 0; nt < 9; ++nt)
        #pragma unroll
        for (int i = 0; i < 4; ++i) {
            float pe = __expf(lgt[nt][i] - m);
            lgt[nt][i] = pe;
            s += pe;
        }
    s += __shfl_xor(s, 16);
    s += __shfl_xor(s, 32);
    const float inv = 1.f / s;

    // ---- write FULL P tile once: pw[q=lq][k 0..143], stride 168 ----
    short* pw = pws + wid * 16 * 168;
    #pragma unroll
    for (int nt = 0; nt < 9; ++nt) {
        *(unsigned*)&pw[lq * 168 + nt * 16 + 4 * lg]     = pk2(lgt[nt][0], lgt[nt][1]);
        *(unsigned*)&pw[lq * 168 + nt * 16 + 4 * lg + 2] = pk2(lgt[nt][2], lgt[nt][3]);
    }

    // ---- PV: 5 independent ds_read_b128 + global V^T frags + MFMA ----
    const short* vsrc = vT_ws + (long)(bwL * 6 + h) * 4608;
    f32x4 o[2] = {};
    const bf16x8 zb = {};
    #pragma unroll
    for (int kt = 0; kt < 5; ++kt) {
        bf16x8 bpf = *(const bf16x8*)&pw[lq * 168 + kt * 32 + 8 * lg];
        #pragma unroll
        for (int et = 0; et < 2; ++et) {
            bf16x8 av = *(const bf16x8*)&vsrc[(et * 16 + lq) * N_TOK + kt * 32 + 8 * lg];
            bf16x8 aa = av, bb = bpf;
            if (kt == 4 && lg >= 2) { aa = zb; bb = zb; }   // keys 144..159
            o[et] = MFMA(aa, bb, o[et]);
        }
    }

    // ---- write tmp[bwL][q][h*32 + e] (short4) ----
    short* tb = tmp + ((long)bwL * N_TOK + q) * DIM + h * 32;
    #pragma unroll
    for (int et = 0; et < 2; ++et) {
        short4 sx = { f2bf(o[et][0] * inv), f2bf(o[et][1] * inv),
                      f2bf(o[et][2] * inv), f2bf(o[et][3] * inv) };
        *(short4*)&tb[et * 16 + 4 * lg] = sx;
    }
}

// ---------------------------------------------------------------------------
// K3: output projection. Block = (bwL, m-third), 3 waves, wave = 16 rows.
// ---------------------------------------------------------------------------
__global__ __launch_bounds__(192)
void proj_k(const short* __restrict__ tmp, const short* __restrict__ pwt,
            const float* __restrict__ proj_b, float* __restrict__ out, int bw0) {
    const int bid = blockIdx.x;
    const int mthird = bid % 3;
    const int bwL = bid / 3;
    const int bwG = bw0 + bwL;
    const int tid = threadIdx.x;
    const int wid = tid >> 6, lane = tid & 63, lq = lane & 15, lg = lane >> 4;
    const int m0 = (mthird * 3 + wid) * 16;
    const short* tb = tmp + (long)bwL * N_TOK * DIM;

    f32x4 acc[12] = {};
    for (int ks = 0; ks < 6; ++ks) {
        const int k0 = ks * 32 + 8 * lg;
        bf16x8 a = *(const bf16x8*)&tb[(m0 + lq) * DIM + k0];
        #pragma unroll
        for (int nt = 0; nt < 12; ++nt) {
            bf16x8 b = *(const bf16x8*)&pwt[(nt * 16 + lq) * DIM + k0];
            acc[nt] = MFMA(a, b, acc[nt]);
        }
    }
    float* ob = out + (long)bwG * N_TOK * DIM;
    #pragma unroll
    for (int nt = 0; nt < 12; ++nt) {
        float pb = proj_b[nt * 16 + lq];
        #pragma unroll
        for (int i = 0; i < 4; ++i)
            ob[(m0 + 4 * lg + i) * DIM + nt * 16 + lq] = acc[nt][i] + pb;
    }
}

// ---------------------------------------------------------------------------
extern "C" void kernel_launch(void* const* d_in, const int* in_sizes, int n_in,
                              void* d_out, int out_size, void* d_ws, size_t ws_size,
                              hipStream_t stream) {
    const float* x        = (const float*)d_in[0];
    const float* mask     = (const float*)d_in[1];
    const float* qkv_w    = (const float*)d_in[2];
    const float* qkv_b    = (const float*)d_in[3];
    const float* table    = (const float*)d_in[4];
    const float* proj_w   = (const float*)d_in[5];
    const float* proj_b   = (const float*)d_in[6];
    const int*   pos_index= (const int*)d_in[7];
    float* out = (float*)d_out;

    // ws layout (bf16 shorts), total 122.38 MB (proven footprint):
    //  bias_bf  [384][144*144]            15.93 MB
    //  projw_bf [192*192]                  0.07 MB
    //  qkvw_bf  [576*192]                  0.22 MB
    //  tmp_ws   [CHUNK x 144 x 192]       26.54 MB (per chunk)
    //  qk_ws    [CHUNK*6][2][144][32]     53.08 MB (per chunk)
    //  vT_ws    [CHUNK*6][32][144]        26.54 MB (per chunk)
    short* bias_bf  = (short*)d_ws;
    short* projw_bf = bias_bf + (size_t)384 * N_TOK * N_TOK;
    short* qkvw_bf  = projw_bf + 36864;
    short* tmp_ws   = qkvw_bf + 110592;
    short* qk_ws    = tmp_ws + (size_t)CHUNK * N_TOK * DIM;
    short* vT_ws    = qk_ws + (size_t)CHUNK * 6 * 2 * 4608;

    bias_k<<<384, 256, 0, stream>>>(table, pos_index, bias_bf);
    cvt_k<<<144, 256, 0, stream>>>(proj_w, projw_bf, DIM * DIM);
    cvt_k<<<432, 256, 0, stream>>>(qkv_w, qkvw_bf, 3 * DIM * DIM);

    for (int c = 0; c < 2; ++c) {
        const int bw0 = c * CHUNK;
        qkvs192_k<<<CHUNK * 9, 192, 0, stream>>>(x, qkvw_bf, qkv_b,
                                                 qk_ws, vT_ws, bw0);
        attn3w_k<<<CHUNK * 18, 192, 0, stream>>>(qk_ws, vT_ws, bias_bf, mask,
                                                 tmp_ws, bw0);
        proj_k<<<CHUNK * 3, 192, 0, stream>>>(tmp_ws, projw_bf, proj_b, out, bw0);
    }
}

// Round 14
// 459.449 us; speedup vs baseline: 1.1671x; 1.0111x over previous
//
#include <hip/hip_runtime.h>
#include <hip/hip_bf16.h>

#define HEADS 6
#define N_TOK 144
#define DIM   192
#define NW    64
#define NB    15
#define NBW   (NB * NW)          // 960
#define CHUNK 480                // bw per chunk (2 chunks)

typedef __attribute__((ext_vector_type(8))) short bf16x8;
typedef __attribute__((ext_vector_type(4))) float f32x4;

#define MFMA(a, b, c) __builtin_amdgcn_mfma_f32_16x16x32_bf16(a, b, c, 0, 0, 0)

static __device__ __forceinline__ short f2bf(float f) {
    __hip_bfloat16 h = __float2bfloat16(f);          // RNE, v_cvt hardware op
    return *reinterpret_cast<short*>(&h);
}
static __device__ __forceinline__ float bf2f(short s) {
    union { unsigned u; float f; } v;
    v.u = ((unsigned)(unsigned short)s) << 16;
    return v.f;
}
static __device__ __forceinline__ unsigned pk2(float a, float b) {
    __hip_bfloat162 h = __float22bfloat162_rn(make_float2(a, b));  // 1 VALU op
    return *reinterpret_cast<unsigned*>(&h);
}

// ---------------------------------------------------------------------------
// K0a: bias gather -> bf16, layout [(w*6+h)][i*144+j].
// ---------------------------------------------------------------------------
__global__ __launch_bounds__(256)
void bias_k(const float* __restrict__ table, const int* __restrict__ pos_index,
            short* __restrict__ bias_bf) {
    const int t = blockIdx.x;                      // w*6+h, 0..383
    for (int e = threadIdx.x; e < N_TOK * N_TOK; e += 256) {
        int idx = pos_index[e];
        bias_bf[(long)t * (N_TOK * N_TOK) + e] = f2bf(table[(long)idx * 384 + t]);
    }
}

// K0b: f32 -> bf16 scalar copy (weights)
__global__ __launch_bounds__(256)
void cvt_k(const float* __restrict__ w, short* __restrict__ o, int n) {
    int i = blockIdx.x * 256 + threadIdx.x;
    if (i < n) o[i] = f2bf(w[i]);
}

// ---------------------------------------------------------------------------
// K1 (R13 core, hw-cvt): QKV GEMM, 192-thread blocks. Block = (bwL, sel, mg):
// 3 waves (ng); wave tile 48x64. x staged f32->bf16 in-block; W B-frags from
// L2-resident bf16 qkv_w. Epilogue via LDS restage -> coalesced stores.
// ---------------------------------------------------------------------------
__global__ __launch_bounds__(192)
void qkvs192_k(const float* __restrict__ x, const short* __restrict__ qkvw_bf,
               const float* __restrict__ qkv_b, short* __restrict__ qk_ws,
               short* __restrict__ vT_ws, int bw0) {
    __shared__ short xl[192 * 56];   // 21,504 B; [48][200] stage / [192][56] v

    const int p = blockIdx.x;
    const int l = (p & 7) * 540 + (p >> 3);    // bijective: 4320 = 8*540
    const int mg  = l % 3;
    const int sel = (l / 3) % 3;
    const int bwL = l / 9;
    const int bwG = bw0 + bwL;
    const int tid = threadIdx.x;

    // ---- stage x rows [mg*48, +48) as bf16 [48][200] ----
    {
        const float* xg = x + ((long)bwG * N_TOK + mg * 48) * DIM;
        for (int u = tid * 4; u < 48 * DIM; u += 192 * 4) {
            float4 f = *(const float4*)&xg[u];
            uint2 s = make_uint2(pk2(f.x, f.y), pk2(f.z, f.w));
            int r = u / DIM, c = u - r * DIM;
            *(uint2*)&xl[r * 200 + c] = s;
        }
    }
    __syncthreads();

    const int wid = tid >> 6, lane = tid & 63, lq = lane & 15, lg = lane >> 4;
    const int ng = wid;

    f32x4 acc[3][4] = {};
    for (int ks = 0; ks < 6; ++ks) {
        const int k0 = ks * 32 + 8 * lg;
        bf16x8 av[3], bv[4];
        #pragma unroll
        for (int mt = 0; mt < 3; ++mt)
            av[mt] = *(const bf16x8*)&xl[(mt * 16 + lq) * 200 + k0];
        #pragma unroll
        for (int nt = 0; nt < 4; ++nt)
            bv[nt] = *(const bf16x8*)&qkvw_bf[
                ((long)sel * 192 + ng * 64 + nt * 16 + lq) * 192 + k0];
        #pragma unroll
        for (int mt = 0; mt < 3; ++mt)
            #pragma unroll
            for (int nt = 0; nt < 4; ++nt)
                acc[mt][nt] = MFMA(av[mt], bv[nt], acc[mt][nt]);
    }
    __syncthreads();   // done reading xl -> reuse for restage

    const float scale = 0.17677669529663687f;   // 32^-0.5

    if (sel < 2) {
        // ---- row-major restage [48][200] ----
        #pragma unroll
        for (int nt = 0; nt < 4; ++nt) {
            const int cd = ng * 64 + nt * 16 + lq;          // 0..191
            const float bb = qkv_b[sel * 192 + cd];
            #pragma unroll
            for (int mt = 0; mt < 3; ++mt)
                #pragma unroll
                for (int i = 0; i < 4; ++i) {
                    int row = mt * 16 + 4 * lg + i;          // 0..47
                    float v = acc[mt][nt][i] + bb;
                    if (sel == 0) v *= scale;
                    xl[row * 200 + cd] = f2bf(v);
                }
        }
        __syncthreads();
        short* ob = qk_ws + (long)bwL * 6 * 2 * 4608 + (long)sel * 4608
                  + mg * 48 * 32;
        #pragma unroll
        for (int j = 0; j < 6; ++j) {
            int u = (j * 192 + tid) * 8;        // 0..9215
            int h = u / 1536, rem = u - h * 1536;
            int row = rem >> 5, e = rem & 31;
            *(bf16x8*)&ob[(long)h * 2 * 4608 + row * 32 + e] =
                *(const bf16x8*)&xl[row * 200 + h * 32 + e];
        }
    } else {
        // ---- col-major restage [192][56] ----
        #pragma unroll
        for (int nt = 0; nt < 4; ++nt) {
            const int cd = ng * 64 + nt * 16 + lq;          // 0..191
            const float bb = qkv_b[2 * 192 + cd];
            #pragma unroll
            for (int mt = 0; mt < 3; ++mt)
                #pragma unroll
                for (int i = 0; i < 4; ++i) {
                    int row = mt * 16 + 4 * lg + i;          // 0..47
                    xl[cd * 56 + row] = f2bf(acc[mt][nt][i] + bb);
                }
        }
        __syncthreads();
        short* ob = vT_ws + (long)bwL * 6 * 4608 + mg * 48;
        #pragma unroll
        for (int j = 0; j < 6; ++j) {
            int u = (j * 192 + tid) * 8;        // 0..9215
            int he = u / 48, row0 = u - he * 48;
            *(bf16x8*)&ob[(long)he * 144 + row0] =
                *(const bf16x8*)&xl[he * 56 + row0];
        }
    }
}

// ---------------------------------------------------------------------------
// K2: 3-wave attention, barrier-free, ILP-opened. Block = (bwL, head, third).
// launch_bounds (192,4) -> <=128 VGPR so the scheduler can hoist loads.
// V^T frags prefetched to regs BEFORE softmax (independent); hw cvt_pk for
// P-pack and output; LDS pad zeroed once -> no in-loop tail masking of P;
// setprio around MFMA clusters.
// ---------------------------------------------------------------------------
__global__ __launch_bounds__(192, 4)
void attn3w_k(const short* __restrict__ qk_ws, const short* __restrict__ vT_ws,
              const short* __restrict__ bias_bf, const float* __restrict__ mask,
              short* __restrict__ tmp, int bw0) {
    __shared__ short pws[3 * 16 * 168];   // 16,128 B

    // XCD chunking: grid = CHUNK*18 = 8640 = 8 * 1080
    const int p = blockIdx.x;
    const int l = (p & 7) * 1080 + (p >> 3);
    const int third = l % 3;
    const int h     = (l / 3) % HEADS;
    const int bwL   = l / 18;
    const int bwG   = bw0 + bwL;
    const int lane = threadIdx.x & 63, lq = lane & 15, lg = lane >> 4;
    const int wid = threadIdx.x >> 6;
    const int mt9 = third * 3 + wid;       // m-tile 0..8
    const int q = mt9 * 16 + lq;            // this lane's query row
    const int w = bwG & 63;

    const short* qb = qk_ws + (long)(bwL * 6 + h) * 2 * 4608;
    const short* kb = qb + 4608;

    // ---- QK^T (swapped: A=K tile, B=Q tile) ----
    const f32x4 zf = {};
    bf16x8 bq = *(const bf16x8*)&qb[q * 32 + 8 * lg];
    f32x4 lgt[9];
    __builtin_amdgcn_s_setprio(1);
    #pragma unroll
    for (int nt = 0; nt < 9; ++nt) {
        bf16x8 ak = *(const bf16x8*)&kb[(nt * 16 + lq) * 32 + 8 * lg];
        lgt[nt] = MFMA(ak, bq, zf);
    }
    __builtin_amdgcn_s_setprio(0);

    // ---- V^T prefetch to regs (independent of softmax; hides L2/HBM) ----
    const short* vsrc = vT_ws + (long)(bwL * 6 + h) * 4608;
    bf16x8 vfr[10];
    #pragma unroll
    for (int kt = 0; kt < 4; ++kt)
        #pragma unroll
        for (int et = 0; et < 2; ++et)
            vfr[kt * 2 + et] =
                *(const bf16x8*)&vsrc[(et * 16 + lq) * N_TOK + kt * 32 + 8 * lg];
    {
        const int lgc = (lg < 2) ? lg : 0;   // clamp tail load in-bounds
        #pragma unroll
        for (int et = 0; et < 2; ++et)
            vfr[8 + et] =
                *(const bf16x8*)&vsrc[(et * 16 + lq) * N_TOK + 128 + 8 * lgc];
        if (lg >= 2) {
            const bf16x8 zb = {};
            vfr[8] = zb; vfr[9] = zb;        // keys 144..159 are zero
        }
    }

    // ---- + bias (short4) + mask (float4) ----
    const short* bp = bias_bf + (long)(w * 6 + h) * (N_TOK * N_TOK)
                    + q * N_TOK + 4 * lg;
    const float* mp = mask + (long)bwG * (N_TOK * N_TOK) + q * N_TOK + 4 * lg;
    #pragma unroll
    for (int nt = 0; nt < 9; ++nt) {
        short4 bs = *(const short4*)&bp[nt * 16];
        float4 mf = *(const float4*)&mp[nt * 16];
        lgt[nt][0] += bf2f(bs.x) + mf.x;
        lgt[nt][1] += bf2f(bs.y) + mf.y;
        lgt[nt][2] += bf2f(bs.z) + mf.z;
        lgt[nt][3] += bf2f(bs.w) + mf.w;
    }

    // ---- softmax over k (36 in-lane + xor16/xor32) ----
    float m = lgt[0][0];
    #pragma unroll
    for (int nt = 0; nt < 9; ++nt)
        #pragma unroll
        for (int i = 0; i < 4; ++i) m = fmaxf(m, lgt[nt][i]);
    m = fmaxf(m, __shfl_xor(m, 16));
    m = fmaxf(m, __shfl_xor(m, 32));
    float s = 0.f;
    #pragma unroll
    for (int nt = 0; nt < 9; ++nt)
        #pragma unroll
        for (int i = 0; i < 4; ++i) {
            float pe = __expf(lgt[nt][i] - m);
            lgt[nt][i] = pe;
            s += pe;
        }
    s += __shfl_xor(s, 16);
    s += __shfl_xor(s, 32);
    const float inv = 1.f / s;

    // ---- write FULL P tile once (hw cvt_pk), zero pad cols 144..159 ----
    short* pw = pws + wid * 16 * 168;
    #pragma unroll
    for (int nt = 0; nt < 9; ++nt) {
        uint2 u2 = make_uint2(pk2(lgt[nt][0], lgt[nt][1]),
                              pk2(lgt[nt][2], lgt[nt][3]));
        *(uint2*)&pw[lq * 168 + nt * 16 + 4 * lg] = u2;
    }
    *(uint2*)&pw[lq * 168 + 144 + 4 * lg] = make_uint2(0u, 0u);

    // ---- PV: 5 ds_read_b128 + prefetched V regs + MFMA (no masking) ----
    f32x4 o[2] = {};
    __builtin_amdgcn_s_setprio(1);
    #pragma unroll
    for (int kt = 0; kt < 5; ++kt) {
        bf16x8 bpf = *(const bf16x8*)&pw[lq * 168 + kt * 32 + 8 * lg];
        #pragma unroll
        for (int et = 0; et < 2; ++et)
            o[et] = MFMA(vfr[kt * 2 + et], bpf, o[et]);
    }
    __builtin_amdgcn_s_setprio(0);

    // ---- write tmp[bwL][q][h*32 + e] (8B packed) ----
    short* tb = tmp + ((long)bwL * N_TOK + q) * DIM + h * 32;
    #pragma unroll
    for (int et = 0; et < 2; ++et) {
        uint2 u2 = make_uint2(pk2(o[et][0] * inv, o[et][1] * inv),
                              pk2(o[et][2] * inv, o[et][3] * inv));
        *(uint2*)&tb[et * 16 + 4 * lg] = u2;
    }
}

// ---------------------------------------------------------------------------
// K3: output projection. Block = (bwL, m-third), 3 waves, wave = 16 rows.
// ---------------------------------------------------------------------------
__global__ __launch_bounds__(192)
void proj_k(const short* __restrict__ tmp, const short* __restrict__ pwt,
            const float* __restrict__ proj_b, float* __restrict__ out, int bw0) {
    const int bid = blockIdx.x;
    const int mthird = bid % 3;
    const int bwL = bid / 3;
    const int bwG = bw0 + bwL;
    const int tid = threadIdx.x;
    const int wid = tid >> 6, lane = tid & 63, lq = lane & 15, lg = lane >> 4;
    const int m0 = (mthird * 3 + wid) * 16;
    const short* tb = tmp + (long)bwL * N_TOK * DIM;

    f32x4 acc[12] = {};
    for (int ks = 0; ks < 6; ++ks) {
        const int k0 = ks * 32 + 8 * lg;
        bf16x8 a = *(const bf16x8*)&tb[(m0 + lq) * DIM + k0];
        #pragma unroll
        for (int nt = 0; nt < 12; ++nt) {
            bf16x8 b = *(const bf16x8*)&pwt[(nt * 16 + lq) * DIM + k0];
            acc[nt] = MFMA(a, b, acc[nt]);
        }
    }
    float* ob = out + (long)bwG * N_TOK * DIM;
    #pragma unroll
    for (int nt = 0; nt < 12; ++nt) {
        float pb = proj_b[nt * 16 + lq];
        #pragma unroll
        for (int i = 0; i < 4; ++i)
            ob[(m0 + 4 * lg + i) * DIM + nt * 16 + lq] = acc[nt][i] + pb;
    }
}

// ---------------------------------------------------------------------------
extern "C" void kernel_launch(void* const* d_in, const int* in_sizes, int n_in,
                              void* d_out, int out_size, void* d_ws, size_t ws_size,
                              hipStream_t stream) {
    const float* x        = (const float*)d_in[0];
    const float* mask     = (const float*)d_in[1];
    const float* qkv_w    = (const float*)d_in[2];
    const float* qkv_b    = (const float*)d_in[3];
    const float* table    = (const float*)d_in[4];
    const float* proj_w   = (const float*)d_in[5];
    const float* proj_b   = (const float*)d_in[6];
    const int*   pos_index= (const int*)d_in[7];
    float* out = (float*)d_out;

    // ws layout (bf16 shorts), total 122.38 MB (proven footprint):
    short* bias_bf  = (short*)d_ws;
    short* projw_bf = bias_bf + (size_t)384 * N_TOK * N_TOK;
    short* qkvw_bf  = projw_bf + 36864;
    short* tmp_ws   = qkvw_bf + 110592;
    short* qk_ws    = tmp_ws + (size_t)CHUNK * N_TOK * DIM;
    short* vT_ws    = qk_ws + (size_t)CHUNK * 6 * 2 * 4608;

    bias_k<<<384, 256, 0, stream>>>(table, pos_index, bias_bf);
    cvt_k<<<144, 256, 0, stream>>>(proj_w, projw_bf, DIM * DIM);
    cvt_k<<<432, 256, 0, stream>>>(qkv_w, qkvw_bf, 3 * DIM * DIM);

    for (int c = 0; c < 2; ++c) {
        const int bw0 = c * CHUNK;
        qkvs192_k<<<CHUNK * 9, 192, 0, stream>>>(x, qkvw_bf, qkv_b,
                                                 qk_ws, vT_ws, bw0);
        attn3w_k<<<CHUNK * 18, 192, 0, stream>>>(qk_ws, vT_ws, bias_bf, mask,
                                                 tmp_ws, bw0);
        proj_k<<<CHUNK * 3, 192, 0, stream>>>(tmp_ws, projw_bf, proj_b, out, bw0);
    }
}